// Round 4
// baseline (892.840 us; speedup 1.0000x reference)
//
#include <hip/hip_runtime.h>
#include <math.h>

#define NN 50000
#define DD 128
#define KK 16
#define CC 8
#define NCH 8                 // chunks of 16 floats: h stored [NCH][NN][16] (3.2MB/chunk < 4MiB L2)
#define NB8 782               // ceil(NN/64) node-blocks per chunk

// ---- ws layout (bytes) ----
#define A_OFF    0u
#define B_OFF    (NN*DD*4u)               // 25,600,000
#define CENT_OFF (2u*NN*DD*4u)            // 51,200,000
#define Z0_OFF   (CENT_OFF + NN*4u)
#define Z1_OFF   (Z0_OFF + NN*4u)
#define F1_OFF   (Z1_OFF + NN*4u)
#define F2_OFF   (F1_OFF + NN*4u)
#define SU_OFF   (F2_OFF + NN*4u)         // 2 x u32 (exact f1 sums)
#define SD_OFF   (SU_OFF + 8u)            // 2 x double (f2 sums)
#define OACC_OFF (SD_OFF + 16u)           // 8 x double (output accum)
#define TICK_OFF (OACC_OFF + 64u)         // 1 x u32 ticket

// ---------------- feat @ W_gcn -> A (chunk-major [c][node][16]) ----------------
__global__ __launch_bounds__(256) void k_gemm(const float* __restrict__ feat,
    const float* __restrict__ W, float* __restrict__ A, double* __restrict__ oacc,
    unsigned* __restrict__ tick)
{
    __shared__ __align__(16) float sW[DD*DD];
    __shared__ float sF[64][DD+1];
    const int t = threadIdx.x;
    const int base = blockIdx.x * 64;
    if (blockIdx.x == 0) {
        if (t < CC) oacc[t] = 0.0;
        if (t == CC) *tick = 0u;
    }

    const float4* W4 = (const float4*)W;
    float4* sW4 = (float4*)sW;
    #pragma unroll
    for (int i = 0; i < 16; ++i) sW4[t + i*256] = W4[t + i*256];

    const float4* F4 = (const float4*)feat;
    #pragma unroll
    for (int e = t; e < 64*32; e += 256) {
        int row = e >> 5, q = e & 31;
        float4 v = make_float4(0.f,0.f,0.f,0.f);
        if (base + row < NN) v = F4[(size_t)(base + row)*32 + q];
        sF[row][q*4+0] = v.x; sF[row][q*4+1] = v.y;
        sF[row][q*4+2] = v.z; sF[row][q*4+3] = v.w;
    }
    __syncthreads();

    const int cg = t & 15;       // cols cg*8 .. cg*8+7
    const int ng = t >> 4;       // nodes ng*4 .. ng*4+3
    const int cb = cg * 8;
    float acc[4][8];
    #pragma unroll
    for (int j=0;j<4;++j)
        #pragma unroll
        for (int c=0;c<8;++c) acc[j][c]=0.f;

    #pragma unroll 4
    for (int d = 0; d < DD; ++d) {
        float4 wa = *(const float4*)&sW[d*DD + cb];
        float4 wb = *(const float4*)&sW[d*DD + cb + 4];
        #pragma unroll
        for (int j=0;j<4;++j) {
            float f = sF[ng*4+j][d];
            acc[j][0] += f*wa.x; acc[j][1] += f*wa.y;
            acc[j][2] += f*wa.z; acc[j][3] += f*wa.w;
            acc[j][4] += f*wb.x; acc[j][5] += f*wb.y;
            acc[j][6] += f*wb.z; acc[j][7] += f*wb.w;
        }
    }
    const int ch = cb >> 4;        // 16-float chunk of this 8-col group
    const int co = cb & 15;        // offset within chunk (0 or 8)
    #pragma unroll
    for (int j=0;j<4;++j) {
        int node = base + ng*4 + j;
        if (node < NN) {
            float4* dst = (float4*)&A[((size_t)ch*NN + node)*16 + co];
            dst[0] = make_float4(acc[j][0],acc[j][1],acc[j][2],acc[j][3]);
            dst[1] = make_float4(acc[j][4],acc[j][5],acc[j][6],acc[j][7]);
        }
    }
}

// ---------------- h0 = gather-sum(A) + b_gcn (chunked); z0 = 1 ----------------
// grid = NCH * NB8, chunk-major so each 3.2MB chunk is per-XCD-L2 resident.
__global__ __launch_bounds__(256) void k_agg0(const float4* __restrict__ A4,
    const int* __restrict__ nb, const float* __restrict__ bg,
    float4* __restrict__ H4, float* __restrict__ zold)
{
    const int t = threadIdx.x;
    const int c = blockIdx.x / NB8;
    const int nbase = (blockIdx.x % NB8) * 64;
    __shared__ int sIdx[64*17];               // padded: 16 ints + 1 to kill bank conflicts
    {
        int nl = t >> 2, k4 = (t & 3) * 4;
        if (nbase + nl < NN) {
            int4 v = ((const int4*)(nb + (size_t)nbase*KK))[t];
            sIdx[nl*17 + k4 + 0] = v.x; sIdx[nl*17 + k4 + 1] = v.y;
            sIdx[nl*17 + k4 + 2] = v.z; sIdx[nl*17 + k4 + 3] = v.w;
        }
    }
    __syncthreads();
    const int nl = t >> 2;          // node-local 0..63
    const int q  = t & 3;           // float4 index within 16-float chunk row
    const int node = nbase + nl;
    if (node >= NN) return;
    float4 acc = ((const float4*)bg)[c*4 + q];
    #pragma unroll
    for (int k=0;k<KK;++k) {
        int idx = sIdx[nl*17 + k];
        float4 v = A4[((size_t)c*NN + idx)*4 + q];
        acc.x += v.x; acc.y += v.y; acc.z += v.z; acc.w += v.w;
    }
    H4[((size_t)c*NN + node)*4 + q] = acc;
    if (c == 0 && q == 0) zold[node] = 1.0f;
}

// ---------------- center = argmax(h@Wy+by) (softmax skipped: monotonic) ----------------
__global__ __launch_bounds__(256) void k_center(const float* __restrict__ H,
    const float* __restrict__ Wy, const float* __restrict__ by,
    int* __restrict__ center, unsigned* __restrict__ su, double* __restrict__ sd)
{
    const int t = threadIdx.x;
    if (blockIdx.x == 0) {          // zero the per-iteration stat accumulators
        if (t < 2) su[t] = 0u;
        if (t >= 2 && t < 4) sd[t-2] = 0.0;
    }
    __shared__ float sH[64][DD+1];
    __shared__ __align__(16) float sWy[DD*CC];
    __shared__ float sby[CC];
    const int base = blockIdx.x * 64;
    const float4* H4 = (const float4*)H;
    #pragma unroll
    for (int e = t; e < 64*32; e += 256) {
        int row = e >> 5, q = e & 31;
        int ch = q >> 2, q4 = q & 3;
        float4 v = make_float4(0.f,0.f,0.f,0.f);
        if (base + row < NN) v = H4[((size_t)ch*NN + base+row)*4 + q4];
        sH[row][q*4+0] = v.x; sH[row][q*4+1] = v.y;
        sH[row][q*4+2] = v.z; sH[row][q*4+3] = v.w;
    }
    ((float4*)sWy)[t] = ((const float4*)Wy)[t & 255];
    if (t < CC) sby[t] = by[t];
    __syncthreads();

    const int nl = t >> 2;          // node-local 0..63
    const int c0 = (t & 3) * 2;     // this lane handles classes c0, c0+1
    float a0 = 0.f, a1 = 0.f;
    #pragma unroll 8
    for (int d = 0; d < DD; ++d) {
        float f = sH[nl][d];
        a0 += f * sWy[d*CC + c0];
        a1 += f * sWy[d*CC + c0 + 1];
    }
    a0 += sby[c0]; a1 += sby[c0+1];
    float bv = a0; int bi = c0;
    if (a1 > bv) { bv = a1; bi = c0 + 1; }
    #pragma unroll
    for (int off = 1; off < 4; off <<= 1) {
        float ov = __shfl_xor(bv, off, 64);
        int   oi = __shfl_xor(bi, off, 64);
        if (ov > bv || (ov == bv && oi < bi)) { bv = ov; bi = oi; }
    }
    const int node = base + nl;
    if ((t & 3) == 0 && node < NN) center[node] = bi;
}

// ---------------- f1, f2 per node + global sums (u32 exact / f64) ----------------
__global__ __launch_bounds__(256) void k_stats(const int* __restrict__ center,
    const int* __restrict__ nb, float* __restrict__ f1o, float* __restrict__ f2o,
    unsigned* __restrict__ su, double* __restrict__ sd)
{
    const int t = threadIdx.x;
    const int i = blockIdx.x*256 + t;
    unsigned uf1 = 0, uf1sq = 0;
    double df2 = 0.0, df2sq = 0.0;
    if (i < NN) {
        const int ci = center[i];
        const int* nbi = nb + i*KK;
        unsigned long long cnt = 0ull;        // 8 bits per class, max 16 each
        #pragma unroll
        for (int k=0;k<KK;++k) {
            int p = center[nbi[k]];
            cnt += 1ull << (p*8);
        }
        unsigned c1 = (unsigned)((cnt >> (ci*8)) & 0xFFull);
        float f2 = 0.f;
        #pragma unroll
        for (int c=0;c<CC;++c) {
            float fc = (float)((cnt >> (c*8)) & 0xFFull);
            fc = fmaxf(fc, 1e-5f);            // CLAMP
            f2 -= fc * logf(fc);
        }
        f1o[i] = (float)c1;
        f2o[i] = f2;
        uf1 = c1; uf1sq = c1*c1;
        df2 = (double)f2; df2sq = df2*df2;
    }
    #pragma unroll
    for (int off = 32; off > 0; off >>= 1) {
        uf1   += __shfl_down(uf1,   off, 64);
        uf1sq += __shfl_down(uf1sq, off, 64);
        df2   += __shfl_down(df2,   off, 64);
        df2sq += __shfl_down(df2sq, off, 64);
    }
    __shared__ unsigned r1[4], r1s[4];
    __shared__ double   r2[4], r2s[4];
    const int wid = t >> 6, lane = t & 63;
    if (lane == 0) { r1[wid]=uf1; r1s[wid]=uf1sq; r2[wid]=df2; r2s[wid]=df2sq; }
    __syncthreads();
    if (t == 0) {
        atomicAdd(&su[0], r1[0]+r1[1]+r1[2]+r1[3]);
        atomicAdd(&su[1], r1s[0]+r1s[1]+r1s[2]+r1s[3]);
        atomicAdd(&sd[0], r2[0]+r2[1]+r2[2]+r2[3]);
        atomicAdd(&sd[1], r2s[0]+r2s[1]+r2s[2]+r2s[3]);
    }
}

// ---------------- h_next = h + min(zold, z) * gather-sum(h) (chunked) ----------------
__global__ __launch_bounds__(256) void k_update(const float4* __restrict__ Hin4,
    float4* __restrict__ Hout4, const int* __restrict__ nb,
    const float* __restrict__ f1, const float* __restrict__ f2,
    const float* __restrict__ zr, float* __restrict__ zw,
    const unsigned* __restrict__ su, const double* __restrict__ sd,
    const float* __restrict__ tau1, const float* __restrict__ tau2)
{
    const int t = threadIdx.x;
    const int c = blockIdx.x / NB8;
    const int nbase = (blockIdx.x % NB8) * 64;
    __shared__ int sIdx[64*17];
    {
        int nl = t >> 2, k4 = (t & 3) * 4;
        if (nbase + nl < NN) {
            int4 v = ((const int4*)(nb + (size_t)nbase*KK))[t];
            sIdx[nl*17 + k4 + 0] = v.x; sIdx[nl*17 + k4 + 1] = v.y;
            sIdx[nl*17 + k4 + 2] = v.z; sIdx[nl*17 + k4 + 3] = v.w;
        }
    }
    __syncthreads();
    const int nl = t >> 2;
    const int q  = t & 3;
    const int node = nbase + nl;
    if (node >= NN) return;

    const double invN = 1.0 / (double)NN;
    double mu1  = (double)su[0] * invN;
    double var1 = (double)su[1] * invN - mu1*mu1;
    double is1  = 1.0 / sqrt(var1 + 1e-5);
    double mu2  = sd[0] * invN;
    double var2 = sd[1] * invN - mu2*mu2;
    double is2  = 1.0 / sqrt(var2 + 1e-5);
    float nf1 = (float)(((double)f1[node] - mu1) * is1);
    float nf2 = (float)(((double)f2[node] - mu2) * is2);
    float z = (1.0f/(1.0f + expf(nf1 - tau1[0]))) * (1.0f/(1.0f + expf(nf2 - tau2[0])));
    float gate = fminf(zr[node], z);
    if (c == 0 && q == 0) zw[node] = z;

    float4 acc = make_float4(0.f,0.f,0.f,0.f);
    #pragma unroll
    for (int k=0;k<KK;++k) {
        int idx = sIdx[nl*17 + k];
        float4 v = Hin4[((size_t)c*NN + idx)*4 + q];
        acc.x += v.x; acc.y += v.y; acc.z += v.z; acc.w += v.w;
    }
    float4 h = Hin4[((size_t)c*NN + node)*4 + q];
    h.x += gate*acc.x; h.y += gate*acc.y; h.z += gate*acc.z; h.w += gate*acc.w;
    Hout4[((size_t)c*NN + node)*4 + q] = h;
}

// ---------------- out = sum_r h[r] * Wc[r, :] + bc (fused finalize) ----------------
__global__ __launch_bounds__(256) void k_final(const float* __restrict__ H,
    const float4* __restrict__ Wc4, double* __restrict__ oacc,
    unsigned* __restrict__ tick, const float* __restrict__ bc,
    float* __restrict__ out)
{
    const int t = threadIdx.x;
    float a[8];
    #pragma unroll
    for (int c=0;c<8;++c) a[c]=0.f;
    const int R = NN*DD;
    for (int r = blockIdx.x*256 + t; r < R; r += gridDim.x*256) {
        int node = r >> 7, d = r & 127;
        float h = H[(((d>>4)*NN + node) << 4) + (d & 15)];
        float4 wa = Wc4[(size_t)r*2], wb = Wc4[(size_t)r*2 + 1];
        a[0]+=h*wa.x; a[1]+=h*wa.y; a[2]+=h*wa.z; a[3]+=h*wa.w;
        a[4]+=h*wb.x; a[5]+=h*wb.y; a[6]+=h*wb.z; a[7]+=h*wb.w;
    }
    #pragma unroll
    for (int off = 32; off > 0; off >>= 1)
        #pragma unroll
        for (int c=0;c<8;++c) a[c] += __shfl_down(a[c], off, 64);
    __shared__ double sred[4][8];
    __shared__ int last;
    const int wid = t >> 6, lane = t & 63;
    if (lane == 0) {
        #pragma unroll
        for (int c=0;c<8;++c) sred[wid][c] = (double)a[c];
    }
    __syncthreads();
    if (t < 8) {
        double s = sred[0][t]+sred[1][t]+sred[2][t]+sred[3][t];
        atomicAdd(&oacc[t], s);
    }
    __threadfence();
    if (t == 0) {
        unsigned rank = atomicAdd(tick, 1u);
        last = (rank == (unsigned)(gridDim.x - 1)) ? 1 : 0;
    }
    __syncthreads();
    if (last && t < CC) {
        double v = atomicAdd(&oacc[t], 0.0);   // atomic read, device-coherent
        out[t] = (float)(v + (double)bc[t]);
    }
}

extern "C" void kernel_launch(void* const* d_in, const int* in_sizes, int n_in,
                              void* d_out, int out_size, void* d_ws, size_t ws_size,
                              hipStream_t stream)
{
    const float* feat = (const float*)d_in[0];
    const float* Wg   = (const float*)d_in[1];
    const float* bg   = (const float*)d_in[2];
    const float* Wy   = (const float*)d_in[3];
    const float* by   = (const float*)d_in[4];
    const float* tau1 = (const float*)d_in[5];
    const float* tau2 = (const float*)d_in[6];
    const float* Wc   = (const float*)d_in[7];
    const float* bc   = (const float*)d_in[8];
    const int*   nb   = (const int*)d_in[9];

    char* ws = (char*)d_ws;
    float*    A      = (float*)(ws + A_OFF);
    float*    B      = (float*)(ws + B_OFF);
    int*      center = (int*)(ws + CENT_OFF);
    float*    z0     = (float*)(ws + Z0_OFF);
    float*    z1     = (float*)(ws + Z1_OFF);
    float*    f1     = (float*)(ws + F1_OFF);
    float*    f2     = (float*)(ws + F2_OFF);
    unsigned* su     = (unsigned*)(ws + SU_OFF);
    double*   sd     = (double*)(ws + SD_OFF);
    double*   oacc   = (double*)(ws + OACC_OFF);
    unsigned* tick   = (unsigned*)(ws + TICK_OFF);

    k_gemm<<<(NN + 63)/64, 256, 0, stream>>>(feat, Wg, A, oacc, tick);
    k_agg0<<<NCH*NB8, 256, 0, stream>>>((const float4*)A, nb, bg, (float4*)B, z0);

    float* hcur = B; float* hnext = A;
    float* zcur = z0; float* znext = z1;
    for (int it = 0; it < 3; ++it) {
        k_center<<<(NN + 63)/64, 256, 0, stream>>>(hcur, Wy, by, center, su, sd);
        k_stats<<<(NN + 255)/256, 256, 0, stream>>>(center, nb, f1, f2, su, sd);
        k_update<<<NCH*NB8, 256, 0, stream>>>((const float4*)hcur, (float4*)hnext,
                                              nb, f1, f2, zcur, znext, su, sd, tau1, tau2);
        float* tmp = hcur; hcur = hnext; hnext = tmp;
        tmp = zcur; zcur = znext; znext = tmp;
    }
    k_final<<<2048, 256, 0, stream>>>(hcur, (const float4*)Wc, oacc, tick, bc, (float*)d_out);
}

// Round 5
// 620.415 us; speedup vs baseline: 1.4391x; 1.4391x over previous
//
#include <hip/hip_runtime.h>
#include <math.h>

#define NN 50000
#define DD 128
#define KK 16
#define CC 8
#define NCH 8                 // h stored chunk-major [NCH][NN][16]; 3.2MB/chunk < 4MiB L2
#define NB64 782              // ceil(NN/64)

// ---- ws layout (bytes) ----
#define A_OFF    0u
#define B_OFF    (NN*DD*4u)               // 25,600,000
#define CENT_OFF (2u*NN*DD*4u)            // 51,200,000
#define Z0_OFF   (CENT_OFF + NN*4u)
#define Z1_OFF   (Z0_OFF + NN*4u)
#define F1_OFF   (Z1_OFF + NN*4u)
#define F2_OFF   (F1_OFF + NN*4u)
#define SU_OFF   (F2_OFF + NN*4u)         // 6 x u32 (f1 sums, slot per iter)
#define SD_OFF   (SU_OFF + 32u)           // 6 x double (f2 sums, slot per iter)
#define OACC_OFF (SD_OFF + 48u)           // 8 x double

// ---------------- feat @ W_gcn -> A (chunk-major [c][node][16]) ----------------
__global__ __launch_bounds__(256) void k_gemm(const float* __restrict__ feat,
    const float* __restrict__ W, float* __restrict__ A, double* __restrict__ oacc,
    unsigned* __restrict__ su, double* __restrict__ sd)
{
    __shared__ __align__(16) float sW[DD*DD];
    __shared__ float sF[64][DD+1];
    const int t = threadIdx.x;
    const int base = blockIdx.x * 64;
    if (blockIdx.x == 0) {
        if (t < 8) oacc[t] = 0.0;
        if (t < 6) { su[t] = 0u; sd[t] = 0.0; }
    }

    const float4* W4 = (const float4*)W;
    float4* sW4 = (float4*)sW;
    #pragma unroll
    for (int i = 0; i < 16; ++i) sW4[t + i*256] = W4[t + i*256];

    const float4* F4 = (const float4*)feat;
    #pragma unroll
    for (int e = t; e < 64*32; e += 256) {
        int row = e >> 5, q = e & 31;
        float4 v = make_float4(0.f,0.f,0.f,0.f);
        if (base + row < NN) v = F4[(size_t)(base + row)*32 + q];
        sF[row][q*4+0] = v.x; sF[row][q*4+1] = v.y;
        sF[row][q*4+2] = v.z; sF[row][q*4+3] = v.w;
    }
    __syncthreads();

    const int cg = t & 15;
    const int ng = t >> 4;
    const int cb = cg * 8;
    float acc[4][8];
    #pragma unroll
    for (int j=0;j<4;++j)
        #pragma unroll
        for (int c=0;c<8;++c) acc[j][c]=0.f;

    #pragma unroll 4
    for (int d = 0; d < DD; ++d) {
        float4 wa = *(const float4*)&sW[d*DD + cb];
        float4 wb = *(const float4*)&sW[d*DD + cb + 4];
        #pragma unroll
        for (int j=0;j<4;++j) {
            float f = sF[ng*4+j][d];
            acc[j][0] += f*wa.x; acc[j][1] += f*wa.y;
            acc[j][2] += f*wa.z; acc[j][3] += f*wa.w;
            acc[j][4] += f*wb.x; acc[j][5] += f*wb.y;
            acc[j][6] += f*wb.z; acc[j][7] += f*wb.w;
        }
    }
    const int ch = cb >> 4;
    const int co = cb & 15;
    #pragma unroll
    for (int j=0;j<4;++j) {
        int node = base + ng*4 + j;
        if (node < NN) {
            float4* dst = (float4*)&A[((size_t)ch*NN + node)*16 + co];
            dst[0] = make_float4(acc[j][0],acc[j][1],acc[j][2],acc[j][3]);
            dst[1] = make_float4(acc[j][4],acc[j][5],acc[j][6],acc[j][7]);
        }
    }
}

// ---------------- h0 = gather(A)+bg, fused center0 ----------------
// 782 blocks, all co-resident; chunk loop sweeps 3.2MB chunks in lockstep-ish
// phases so each chunk is L2-resident (replicated per XCD) while being gathered.
__global__ __launch_bounds__(256) void k_agg0(const float4* __restrict__ A4,
    const int* __restrict__ nb, const float* __restrict__ bg,
    const float4* __restrict__ Wy4, const float* __restrict__ by,
    float4* __restrict__ H4, float* __restrict__ zold, int* __restrict__ center)
{
    __shared__ __align__(16) float sWy[DD*CC];
    __shared__ float sby[CC];
    const int t = threadIdx.x;
    ((float4*)sWy)[t] = Wy4[t];
    if (t < CC) sby[t] = by[t];
    __syncthreads();
    const int nl = t >> 2, q = t & 3;
    const int node = blockIdx.x*64 + nl;
    if (node >= NN) return;

    int idx[KK];
    const int4* nbv = (const int4*)(nb + (size_t)node*KK);
    #pragma unroll
    for (int k4 = 0; k4 < 4; ++k4) {
        int4 v = nbv[k4];
        idx[k4*4+0]=v.x; idx[k4*4+1]=v.y; idx[k4*4+2]=v.z; idx[k4*4+3]=v.w;
    }
    float lg[CC];
    #pragma unroll
    for (int c=0;c<CC;++c) lg[c]=0.f;

    for (int c = 0; c < NCH; ++c) {
        float4 acc = ((const float4*)bg)[c*4 + q];
        #pragma unroll
        for (int k=0;k<KK;++k) {
            float4 v = A4[((size_t)c*NN + idx[k])*4 + q];
            acc.x += v.x; acc.y += v.y; acc.z += v.z; acc.w += v.w;
        }
        H4[((size_t)c*NN + node)*4 + q] = acc;
        const int d0 = c*16 + q*4;
        #pragma unroll
        for (int cls=0; cls<CC; ++cls)
            lg[cls] += acc.x*sWy[(d0+0)*CC+cls] + acc.y*sWy[(d0+1)*CC+cls]
                     + acc.z*sWy[(d0+2)*CC+cls] + acc.w*sWy[(d0+3)*CC+cls];
    }
    #pragma unroll
    for (int off=1; off<4; off<<=1)
        #pragma unroll
        for (int cls=0; cls<CC; ++cls) lg[cls] += __shfl_xor(lg[cls], off, 64);
    if (q == 0) {
        float bv = lg[0] + sby[0]; int bi = 0;
        #pragma unroll
        for (int cls=1; cls<CC; ++cls) {
            float v = lg[cls] + sby[cls];
            if (v > bv) { bv = v; bi = cls; }
        }
        center[node] = bi;
        zold[node] = 1.0f;
    }
}

// ---------------- f1, f2 per node + slot sums (u32 exact / f64) ----------------
__global__ __launch_bounds__(256) void k_stats(const int* __restrict__ center,
    const int* __restrict__ nb, float* __restrict__ f1o, float* __restrict__ f2o,
    unsigned* __restrict__ su2, double* __restrict__ sd2)
{
    const int t = threadIdx.x;
    const int i = blockIdx.x*256 + t;
    unsigned uf1 = 0, uf1sq = 0;
    double df2 = 0.0, df2sq = 0.0;
    if (i < NN) {
        const int ci = center[i];
        const int* nbi = nb + i*KK;
        unsigned long long cnt = 0ull;
        #pragma unroll
        for (int k=0;k<KK;++k) {
            int p = center[nbi[k]];
            cnt += 1ull << (p*8);
        }
        unsigned c1 = (unsigned)((cnt >> (ci*8)) & 0xFFull);
        float f2 = 0.f;
        #pragma unroll
        for (int c=0;c<CC;++c) {
            float fc = (float)((cnt >> (c*8)) & 0xFFull);
            fc = fmaxf(fc, 1e-5f);
            f2 -= fc * logf(fc);
        }
        f1o[i] = (float)c1;
        f2o[i] = f2;
        uf1 = c1; uf1sq = c1*c1;
        df2 = (double)f2; df2sq = df2*df2;
    }
    #pragma unroll
    for (int off = 32; off > 0; off >>= 1) {
        uf1   += __shfl_down(uf1,   off, 64);
        uf1sq += __shfl_down(uf1sq, off, 64);
        df2   += __shfl_down(df2,   off, 64);
        df2sq += __shfl_down(df2sq, off, 64);
    }
    __shared__ unsigned r1[4], r1s[4];
    __shared__ double   r2[4], r2s[4];
    const int wid = t >> 6, lane = t & 63;
    if (lane == 0) { r1[wid]=uf1; r1s[wid]=uf1sq; r2[wid]=df2; r2s[wid]=df2sq; }
    __syncthreads();
    if (t == 0) {
        atomicAdd(&su2[0], r1[0]+r1[1]+r1[2]+r1[3]);
        atomicAdd(&su2[1], r1s[0]+r1s[1]+r1s[2]+r1s[3]);
        atomicAdd(&sd2[0], r2[0]+r2[1]+r2[2]+r2[3]);
        atomicAdd(&sd2[1], r2s[0]+r2s[1]+r2s[2]+r2s[3]);
    }
}

// ---------------- h' = h + min(zold,z)*gather(h), fused next-center ----------------
__global__ __launch_bounds__(256) void k_update(const float4* __restrict__ Hin4,
    float4* __restrict__ Hout4, const int* __restrict__ nb,
    const float* __restrict__ f1, const float* __restrict__ f2,
    const float* __restrict__ zr, float* __restrict__ zw,
    const unsigned* __restrict__ su2, const double* __restrict__ sd2,
    const float* __restrict__ tau1, const float* __restrict__ tau2,
    const float4* __restrict__ Wy4, const float* __restrict__ by,
    int* __restrict__ center)
{
    __shared__ __align__(16) float sWy[DD*CC];
    __shared__ float sby[CC];
    const int t = threadIdx.x;
    ((float4*)sWy)[t] = Wy4[t];
    if (t < CC) sby[t] = by[t];
    __syncthreads();
    const int nl = t >> 2, q = t & 3;
    const int node = blockIdx.x*64 + nl;
    if (node >= NN) return;

    const double invN = 1.0 / (double)NN;
    double mu1  = (double)su2[0] * invN;
    double var1 = (double)su2[1] * invN - mu1*mu1;
    double is1  = 1.0 / sqrt(var1 + 1e-5);
    double mu2  = sd2[0] * invN;
    double var2 = sd2[1] * invN - mu2*mu2;
    double is2  = 1.0 / sqrt(var2 + 1e-5);
    float nf1 = (float)(((double)f1[node] - mu1) * is1);
    float nf2 = (float)(((double)f2[node] - mu2) * is2);
    float z = (1.0f/(1.0f + expf(nf1 - tau1[0]))) * (1.0f/(1.0f + expf(nf2 - tau2[0])));
    float gate = fminf(zr[node], z);
    if (q == 0) zw[node] = z;

    int idx[KK];
    const int4* nbv = (const int4*)(nb + (size_t)node*KK);
    #pragma unroll
    for (int k4 = 0; k4 < 4; ++k4) {
        int4 v = nbv[k4];
        idx[k4*4+0]=v.x; idx[k4*4+1]=v.y; idx[k4*4+2]=v.z; idx[k4*4+3]=v.w;
    }
    float lg[CC];
    #pragma unroll
    for (int c=0;c<CC;++c) lg[c]=0.f;

    for (int c = 0; c < NCH; ++c) {
        float4 acc = make_float4(0.f,0.f,0.f,0.f);
        #pragma unroll
        for (int k=0;k<KK;++k) {
            float4 v = Hin4[((size_t)c*NN + idx[k])*4 + q];
            acc.x += v.x; acc.y += v.y; acc.z += v.z; acc.w += v.w;
        }
        float4 h = Hin4[((size_t)c*NN + node)*4 + q];
        h.x += gate*acc.x; h.y += gate*acc.y; h.z += gate*acc.z; h.w += gate*acc.w;
        Hout4[((size_t)c*NN + node)*4 + q] = h;
        const int d0 = c*16 + q*4;
        #pragma unroll
        for (int cls=0; cls<CC; ++cls)
            lg[cls] += h.x*sWy[(d0+0)*CC+cls] + h.y*sWy[(d0+1)*CC+cls]
                     + h.z*sWy[(d0+2)*CC+cls] + h.w*sWy[(d0+3)*CC+cls];
    }
    #pragma unroll
    for (int off=1; off<4; off<<=1)
        #pragma unroll
        for (int cls=0; cls<CC; ++cls) lg[cls] += __shfl_xor(lg[cls], off, 64);
    if (q == 0) {
        float bv = lg[0] + sby[0]; int bi = 0;
        #pragma unroll
        for (int cls=1; cls<CC; ++cls) {
            float v = lg[cls] + sby[cls];
            if (v > bv) { bv = v; bi = cls; }
        }
        center[node] = bi;
    }
}

// ---------------- out accum: sum_r h[r] * Wc[r,:] ----------------
__global__ __launch_bounds__(256) void k_final(const float* __restrict__ H,
    const float4* __restrict__ Wc4, double* __restrict__ oacc)
{
    const int t = threadIdx.x;
    float a[8];
    #pragma unroll
    for (int c=0;c<8;++c) a[c]=0.f;
    const int E = NN*DD/4;               // quads of r
    for (int e = blockIdx.x*256 + t; e < E; e += gridDim.x*256) {
        int r = e*4;
        int node = r >> 7, d = r & 127;
        float4 h4 = *(const float4*)&H[(((size_t)(d>>4)*NN + node) << 4) + (d & 15)];
        float hh[4] = {h4.x, h4.y, h4.z, h4.w};
        #pragma unroll
        for (int j=0;j<4;++j) {
            float h = hh[j];
            float4 wa = Wc4[(size_t)(r+j)*2], wb = Wc4[(size_t)(r+j)*2 + 1];
            a[0]+=h*wa.x; a[1]+=h*wa.y; a[2]+=h*wa.z; a[3]+=h*wa.w;
            a[4]+=h*wb.x; a[5]+=h*wb.y; a[6]+=h*wb.z; a[7]+=h*wb.w;
        }
    }
    #pragma unroll
    for (int off = 32; off > 0; off >>= 1)
        #pragma unroll
        for (int c=0;c<8;++c) a[c] += __shfl_down(a[c], off, 64);
    __shared__ double sred[4][8];
    const int wid = t >> 6, lane = t & 63;
    if (lane == 0) {
        #pragma unroll
        for (int c=0;c<8;++c) sred[wid][c] = (double)a[c];
    }
    __syncthreads();
    if (t < 8) {
        double s = sred[0][t]+sred[1][t]+sred[2][t]+sred[3][t];
        atomicAdd(&oacc[t], s);
    }
}

__global__ void k_fin(const double* __restrict__ oacc, const float* __restrict__ bc,
                      float* __restrict__ out)
{
    const int t = threadIdx.x;
    if (t < CC) out[t] = (float)(oacc[t] + (double)bc[t]);
}

extern "C" void kernel_launch(void* const* d_in, const int* in_sizes, int n_in,
                              void* d_out, int out_size, void* d_ws, size_t ws_size,
                              hipStream_t stream)
{
    const float* feat = (const float*)d_in[0];
    const float* Wg   = (const float*)d_in[1];
    const float* bg   = (const float*)d_in[2];
    const float* Wy   = (const float*)d_in[3];
    const float* by   = (const float*)d_in[4];
    const float* tau1 = (const float*)d_in[5];
    const float* tau2 = (const float*)d_in[6];
    const float* Wc   = (const float*)d_in[7];
    const float* bc   = (const float*)d_in[8];
    const int*   nb   = (const int*)d_in[9];

    char* ws = (char*)d_ws;
    float*    A      = (float*)(ws + A_OFF);
    float*    B      = (float*)(ws + B_OFF);
    int*      center = (int*)(ws + CENT_OFF);
    float*    z0     = (float*)(ws + Z0_OFF);
    float*    z1     = (float*)(ws + Z1_OFF);
    float*    f1     = (float*)(ws + F1_OFF);
    float*    f2     = (float*)(ws + F2_OFF);
    unsigned* su     = (unsigned*)(ws + SU_OFF);
    double*   sd     = (double*)(ws + SD_OFF);
    double*   oacc   = (double*)(ws + OACC_OFF);

    k_gemm<<<NB64, 256, 0, stream>>>(feat, Wg, A, oacc, su, sd);
    k_agg0<<<NB64, 256, 0, stream>>>((const float4*)A, nb, bg, (const float4*)Wy, by,
                                     (float4*)B, z0, center);

    float* hcur = B; float* hnext = A;
    float* zcur = z0; float* znext = z1;
    for (int it = 0; it < 3; ++it) {
        k_stats<<<(NN + 255)/256, 256, 0, stream>>>(center, nb, f1, f2, su + 2*it, sd + 2*it);
        k_update<<<NB64, 256, 0, stream>>>((const float4*)hcur, (float4*)hnext, nb,
                                           f1, f2, zcur, znext, su + 2*it, sd + 2*it,
                                           tau1, tau2, (const float4*)Wy, by, center);
        float* tmp = hcur; hcur = hnext; hnext = tmp;
        tmp = zcur; zcur = znext; znext = tmp;
    }
    k_final<<<2048, 256, 0, stream>>>(hcur, (const float4*)Wc, oacc);
    k_fin<<<1, 64, 0, stream>>>(oacc, bc, (float*)d_out);
}